// Round 2
// baseline (897.807 us; speedup 1.0000x reference)
//
#include <hip/hip_runtime.h>
#include <stdint.h>

// GCN forward, CSR-gather restructure.
// N=100000, E=3000000, G=256, F_IN=64, NHID=32.
// R1 lesson: 96M 4B scatter-atomics ran at the L2 atomic-op ceiling
// (~308 Gops/s, WRITE_SIZE 375MB). This version builds CSR by col and
// gathers: aggregation has ZERO atomics; only 3M+3M build atomics and
// 3.2M pool atomics remain.

#define BLK 256

// K0: cnt histogram over col (all E edges), degf=1 (self-loop), ewc=3 default,
//     thread 0 computes softmax(msg_weights) -> sp[0..2], sp[3]=1.
__global__ void k0_init(const int* __restrict__ col, int* __restrict__ cnt,
                        float* __restrict__ degf, uint8_t* __restrict__ ewc,
                        float* __restrict__ sp, const float* __restrict__ mw,
                        int n_edges, int n_nodes) {
    int i = blockIdx.x * blockDim.x + threadIdx.x;
    if (i < n_edges) {
        atomicAdd(&cnt[col[i]], 1);
        ewc[i] = 3;
    }
    if (i < n_nodes) degf[i] = 1.0f;
    if (i == 0) {
        float a = mw[0], b = mw[1], c = mw[2];
        float m = fmaxf(a, fmaxf(b, c));
        float ea = expf(a - m), eb = expf(b - m), ec = expf(c - m);
        float s = ea + eb + ec;
        sp[0] = ea / s; sp[1] = eb / s; sp[2] = ec / s; sp[3] = 1.0f;
    }
}

// K1: per-mask-entry: record class, accumulate weighted degree at col.
__global__ void k1_class_deg(const int* __restrict__ km, const int* __restrict__ um,
                             const int* __restrict__ om, int s0, int s1, int s2,
                             const int* __restrict__ col, const float* __restrict__ sp,
                             uint8_t* __restrict__ ewc, float* __restrict__ degf) {
    int i = blockIdx.x * blockDim.x + threadIdx.x;
    int total = s0 + s1 + s2;
    if (i >= total) return;
    int e, cls;
    if (i < s0)           { e = km[i];           cls = 0; }
    else if (i < s0 + s1) { e = um[i - s0];      cls = 1; }
    else                  { e = om[i - s0 - s1]; cls = 2; }
    ewc[e] = (uint8_t)cls;
    atomicAdd(&degf[col[e]], sp[cls]);
}

// K2: degf -> dinv in place
__global__ void k2_dinv(float* __restrict__ degf, int n_nodes) {
    int i = blockIdx.x * blockDim.x + threadIdx.x;
    if (i < n_nodes) {
        float d = degf[i];
        degf[i] = (d > 0.0f) ? rsqrtf(d) : 0.0f;
    }
}

// ---- exclusive scan of cnt[N] -> offs[N], 1024 items per 256-thread block ----
__global__ void kscanA(const int* __restrict__ cnt, int* __restrict__ partial, int n) {
    __shared__ int s[BLK];
    int base = blockIdx.x * 1024;
    int t = threadIdx.x;
    int sum = 0;
#pragma unroll
    for (int k = 0; k < 4; ++k) {
        int i = base + t * 4 + k;
        if (i < n) sum += cnt[i];
    }
    s[t] = sum; __syncthreads();
    for (int st = BLK / 2; st > 0; st >>= 1) {
        if (t < st) s[t] += s[t + st];
        __syncthreads();
    }
    if (t == 0) partial[blockIdx.x] = s[0];
}

__global__ void kscanB(int* __restrict__ partial, int nb) {
    __shared__ int s[BLK];
    int t = threadIdx.x;
    s[t] = (t < nb) ? partial[t] : 0; __syncthreads();
    for (int st = 1; st < BLK; st <<= 1) {
        int v = (t >= st) ? s[t - st] : 0;
        __syncthreads();
        s[t] += v;
        __syncthreads();
    }
    if (t < nb) partial[t] = (t == 0) ? 0 : s[t - 1];  // exclusive
}

__global__ void kscanC(const int* __restrict__ cnt, const int* __restrict__ partial,
                       int* __restrict__ offs, int n) {
    __shared__ int s[BLK];
    int base = blockIdx.x * 1024;
    int t = threadIdx.x;
    int i0 = base + t * 4;
    int c[4]; int sum = 0;
#pragma unroll
    for (int k = 0; k < 4; ++k) {
        int i = i0 + k;
        c[k] = (i < n) ? cnt[i] : 0;
        sum += c[k];
    }
    s[t] = sum; __syncthreads();
    for (int st = 1; st < BLK; st <<= 1) {
        int v = (t >= st) ? s[t - st] : 0;
        __syncthreads();
        s[t] += v;
        __syncthreads();
    }
    int ex = (t == 0) ? 0 : s[t - 1];
    ex += partial[blockIdx.x];
#pragma unroll
    for (int k = 0; k < 4; ++k) {
        int i = i0 + k;
        if (i < n) { offs[i] = ex; ex += c[k]; }
    }
}

// K3: fold emb through gcn: Wfull[0,j]=gcn_W[0,j]; Wfull[1+m,j]=emb_W[m,:]@gcn_W[1:,j]
__global__ void k3_weights(const float* __restrict__ emb_W, const float* __restrict__ emb_b,
                           const float* __restrict__ gcn_W,
                           float* __restrict__ Wfull, float* __restrict__ hWbias) {
    int t = threadIdx.x;
    for (int idx = t; idx < 64 * 32; idx += blockDim.x) {
        int k = idx >> 5, j = idx & 31;
        float acc;
        if (k == 0) {
            acc = gcn_W[j];
        } else {
            int m = k - 1;
            acc = 0.0f;
            for (int tt = 0; tt < 63; ++tt)
                acc += emb_W[m * 63 + tt] * gcn_W[(1 + tt) * 32 + j];
        }
        Wfull[idx] = acc;
    }
    if (t < 32) {
        float acc = 0.0f;
        for (int tt = 0; tt < 63; ++tt)
            acc += emb_b[tt] * gcn_W[(1 + tt) * 32 + t];
        hWbias[t] = acc;
    }
}

// K4: hWs[n,:] = dinv[n] * (x[n,:] @ Wfull + hWbias)   -- dinv[row] folded in
__global__ void k4_gemm(const float* __restrict__ x, const float* __restrict__ Wfull,
                        const float* __restrict__ hWbias, const float* __restrict__ dinv,
                        float* __restrict__ hWs, int n_nodes) {
    __shared__ float Wl[64 * 32];
    __shared__ float xs[8 * 64];
    int tid = threadIdx.x;
    for (int idx = tid; idx < 2048; idx += BLK) Wl[idx] = Wfull[idx];
    int rowBase = blockIdx.x * 8;
    for (int idx = tid; idx < 512; idx += BLK) {
        int r = rowBase + (idx >> 6);
        xs[idx] = (r < n_nodes) ? x[(size_t)r * 64 + (idx & 63)] : 0.0f;
    }
    __syncthreads();
    int j = tid & 31, lr = tid >> 5;
    int n = rowBase + lr;
    if (n < n_nodes) {
        float acc = hWbias[j];
#pragma unroll
        for (int k = 0; k < 64; ++k)
            acc += xs[lr * 64 + k] * Wl[k * 32 + j];
        hWs[(size_t)n * 32 + j] = dinv[n] * acc;
    }
}

// K5a: scatter edges into CSR slots: csr[pos] = (row<<2)|cls, pos via offs cursor.
// offs[c] ends up as the END offset for node c.
__global__ void k5a_scatter(const int* __restrict__ row, const int* __restrict__ col,
                            const uint8_t* __restrict__ ewc, int* __restrict__ offs,
                            int* __restrict__ csr, int n_edges) {
    int e = blockIdx.x * blockDim.x + threadIdx.x;
    if (e >= n_edges) return;
    int c = col[e];
    int r = row[e];
    int cls = ewc[e] & 3;
    int pos = atomicAdd(&offs[c], 1);
    csr[pos] = (r << 2) | cls;
}

// K5b: gather-aggregate + self-loop + bias + relu + pool. 32 lanes per node.
// agg[c,j] = dinv[c] * ( sum_p sp[cls_p]*hWs[src_p,j] + hWs[c,j] ) + gcn_b[j]
__global__ void k5b_gather(const int* __restrict__ offs, const int* __restrict__ cnt,
                           const int* __restrict__ csr, const float* __restrict__ hWs,
                           const float* __restrict__ dinv, const float* __restrict__ sp,
                           const float* __restrict__ gcn_b, const int* __restrict__ batch,
                           float* __restrict__ pooled, int n_nodes) {
    int n = blockIdx.x * 8 + (threadIdx.x >> 5);
    int j = threadIdx.x & 31;
    if (n >= n_nodes) return;
    float s0 = sp[0], s1 = sp[1], s2 = sp[2];
    int end = offs[n];            // mutated by k5a: now the end pointer
    int start = end - cnt[n];
    float acc = 0.0f;
    int pk_next = (start < end) ? csr[start] : 0;
    for (int p = start; p < end; ++p) {
        int pk = pk_next;
        if (p + 1 < end) pk_next = csr[p + 1];   // prefetch next entry
        int src = pk >> 2;
        int cls = pk & 3;
        float w = (cls == 0) ? s0 : ((cls == 1) ? s1 : ((cls == 2) ? s2 : 1.0f));
        acc += w * hWs[src * 32 + j];
    }
    float di = dinv[n];
    float a = di * (acc + hWs[n * 32 + j]) + gcn_b[j];
    float hg = fmaxf(a, 0.0f);
    atomicAdd(&pooled[batch[n] * 32 + j], hg);
}

// K7: head: z = relu(pooled @ fc1_W + fc1_b); out = z @ out_W + out_b
__global__ void k7_head(const float* __restrict__ pooled, const float* __restrict__ fc1_W,
                        const float* __restrict__ fc1_b, const float* __restrict__ out_W,
                        const float* __restrict__ out_b, float* __restrict__ out,
                        int n_graphs) {
    __shared__ float Wl[32 * 32];
    __shared__ float bl[32];
    __shared__ float owl[32];
    int t = threadIdx.x;
    for (int idx = t; idx < 1024; idx += BLK) Wl[idx] = fc1_W[idx];
    if (t < 32) { bl[t] = fc1_b[t]; owl[t] = out_W[t]; }
    __syncthreads();
    if (t < n_graphs) {
        float p[32];
#pragma unroll
        for (int k = 0; k < 32; ++k) p[k] = pooled[t * 32 + k];
        float acc = 0.0f;
        for (int j = 0; j < 32; ++j) {
            float z = bl[j];
#pragma unroll
            for (int k = 0; k < 32; ++k) z += p[k] * Wl[k * 32 + j];
            z = fmaxf(z, 0.0f);
            acc += z * owl[j];
        }
        out[t] = acc + out_b[0];
    }
}

extern "C" void kernel_launch(void* const* d_in, const int* in_sizes, int n_in,
                              void* d_out, int out_size, void* d_ws, size_t ws_size,
                              hipStream_t stream) {
    const float* x     = (const float*)d_in[0];
    const int*   ei    = (const int*)d_in[1];
    const int*   batch = (const int*)d_in[2];
    const int*   km    = (const int*)d_in[3];
    const int*   um    = (const int*)d_in[4];
    const int*   om    = (const int*)d_in[5];
    const float* mw    = (const float*)d_in[6];
    const float* emb_W = (const float*)d_in[7];
    const float* emb_b = (const float*)d_in[8];
    const float* gcn_W = (const float*)d_in[9];
    const float* gcn_b = (const float*)d_in[10];
    const float* fc1_W = (const float*)d_in[11];
    const float* fc1_b = (const float*)d_in[12];
    const float* out_W = (const float*)d_in[13];
    const float* out_b = (const float*)d_in[14];

    const int n_nodes  = in_sizes[0] / 64;
    const int n_edges  = in_sizes[1] / 2;
    const int s0 = in_sizes[3], s1 = in_sizes[4], s2 = in_sizes[5];
    const int n_graphs = out_size;  // 256

    const int* row = ei;
    const int* col = ei + n_edges;

    // ---- workspace layout (~29 MB) ----
    char* base = (char*)d_ws;
    float*   degf    = (float*)base;                       base += (size_t)n_nodes * 4;   // -> dinv
    int*     cnt     = (int*)base;                         base += (size_t)n_nodes * 4;
    float*   pooled  = (float*)base;                       base += (size_t)n_graphs * 32 * 4;
    int*     offs    = (int*)base;                         base += (size_t)n_nodes * 4;
    int*     partial = (int*)base;                         base += 256 * 4;
    float*   sp      = (float*)base;                       base += 4 * 4;
    float*   Wfull   = (float*)base;                       base += 2048 * 4;
    float*   hWbias  = (float*)base;                       base += 32 * 4;
    uint8_t* ewc     = (uint8_t*)base;                     base += ((size_t)n_edges + 15) & ~15ull;
    int*     csr     = (int*)base;                         base += (size_t)n_edges * 4;
    float*   hWs     = (float*)base;                       base += (size_t)n_nodes * 32 * 4;

    // zero cnt + pooled in one stream-ordered memset (they are adjacent)
    hipMemsetAsync(cnt, 0, ((size_t)n_nodes + (size_t)n_graphs * 32) * sizeof(float), stream);

    int gmax = ((n_edges > n_nodes ? n_edges : n_nodes) + BLK - 1) / BLK;
    k0_init<<<gmax, BLK, 0, stream>>>(col, cnt, degf, ewc, sp, mw, n_edges, n_nodes);
    k1_class_deg<<<(s0 + s1 + s2 + BLK - 1) / BLK, BLK, 0, stream>>>(
        km, um, om, s0, s1, s2, col, sp, ewc, degf);
    k2_dinv<<<(n_nodes + BLK - 1) / BLK, BLK, 0, stream>>>(degf, n_nodes);

    int nb = (n_nodes + 1023) / 1024;   // 98 for N=100000; kscanB handles nb<=256
    kscanA<<<nb, BLK, 0, stream>>>(cnt, partial, n_nodes);
    kscanB<<<1, BLK, 0, stream>>>(partial, nb);
    kscanC<<<nb, BLK, 0, stream>>>(cnt, partial, offs, n_nodes);

    k3_weights<<<1, BLK, 0, stream>>>(emb_W, emb_b, gcn_W, Wfull, hWbias);
    k4_gemm<<<(n_nodes + 7) / 8, BLK, 0, stream>>>(x, Wfull, hWbias, degf, hWs, n_nodes);

    k5a_scatter<<<(n_edges + BLK - 1) / BLK, BLK, 0, stream>>>(row, col, ewc, offs, csr, n_edges);
    k5b_gather<<<(n_nodes + 7) / 8, BLK, 0, stream>>>(
        offs, cnt, csr, hWs, degf, sp, gcn_b, batch, pooled, n_nodes);

    k7_head<<<1, BLK, 0, stream>>>(pooled, fc1_W, fc1_b, out_W, out_b, (float*)d_out, n_graphs);
}

// Round 3
// 769.152 us; speedup vs baseline: 1.1673x; 1.1673x over previous
//
#include <hip/hip_runtime.h>
#include <stdint.h>

// GCN forward, CSR-gather with XCD-partitioned CSR build.
// N=100000, E=3000000, G=256, F_IN=64, NHID=32.
//
// R1 lesson: 96M 4B scatter-atomics = L2 atomic-op ceiling (312 us).
// R2 lesson: naive CSR build has 16x write amplification (183MB evictions
//   for a 12MB array) because 8 incoherent 4MB L2s thrash on random 4B
//   stores. Fix: partition csr writes by col-range, slice = blockIdx&7
//   (round-robin blockIdx->XCD) so each XCD's slice fits its own L2.

#define BLK 256

// K0: histogram cnt over col; default class 3 (defensive; masks cover all E).
__global__ void k0_hist(const int* __restrict__ col, int* __restrict__ cnt,
                        uint8_t* __restrict__ ewc, int n_edges) {
    int i = blockIdx.x * blockDim.x + threadIdx.x;
    if (i < n_edges) {
        atomicAdd(&cnt[col[i]], 1);
        ewc[i] = 3;
    }
}

// K1: per-mask-entry: record class, accumulate weighted degree at col.
// softmax(mw) recomputed per-thread (3 floats, L2-broadcast).
__global__ void k1_class_deg(const int* __restrict__ km, const int* __restrict__ um,
                             const int* __restrict__ om, int s0, int s1, int s2,
                             const int* __restrict__ col, const float* __restrict__ mw,
                             uint8_t* __restrict__ ewc, float* __restrict__ degf) {
    int i = blockIdx.x * blockDim.x + threadIdx.x;
    int total = s0 + s1 + s2;
    if (i >= total) return;
    float a = mw[0], b = mw[1], c3 = mw[2];
    float m = fmaxf(a, fmaxf(b, c3));
    float ea = __expf(a - m), eb = __expf(b - m), ec = __expf(c3 - m);
    float inv = 1.0f / (ea + eb + ec);
    int e, cls; float w;
    if (i < s0)           { e = km[i];           cls = 0; w = ea * inv; }
    else if (i < s0 + s1) { e = um[i - s0];      cls = 1; w = eb * inv; }
    else                  { e = om[i - s0 - s1]; cls = 2; w = ec * inv; }
    ewc[e] = (uint8_t)cls;
    atomicAdd(&degf[col[e]], w);
}

// K2: dinv = rsqrt(deg + 1)   (+1 = self-loop weight; deg accumulated from 0)
__global__ void k2_dinv(float* __restrict__ degf, int n_nodes) {
    int i = blockIdx.x * blockDim.x + threadIdx.x;
    if (i < n_nodes) degf[i] = rsqrtf(degf[i] + 1.0f);
}

// ---- exclusive scan of cnt[N] -> offs[N], 1024 items per 256-thread block ----
__global__ void kscanA(const int* __restrict__ cnt, int* __restrict__ partial, int n) {
    __shared__ int s[BLK];
    int base = blockIdx.x * 1024;
    int t = threadIdx.x;
    int sum = 0;
#pragma unroll
    for (int k = 0; k < 4; ++k) {
        int i = base + t * 4 + k;
        if (i < n) sum += cnt[i];
    }
    s[t] = sum; __syncthreads();
    for (int st = BLK / 2; st > 0; st >>= 1) {
        if (t < st) s[t] += s[t + st];
        __syncthreads();
    }
    if (t == 0) partial[blockIdx.x] = s[0];
}

__global__ void kscanB(int* __restrict__ partial, int nb) {
    __shared__ int s[BLK];
    int t = threadIdx.x;
    s[t] = (t < nb) ? partial[t] : 0; __syncthreads();
    for (int st = 1; st < BLK; st <<= 1) {
        int v = (t >= st) ? s[t - st] : 0;
        __syncthreads();
        s[t] += v;
        __syncthreads();
    }
    if (t < nb) partial[t] = (t == 0) ? 0 : s[t - 1];  // exclusive
}

__global__ void kscanC(const int* __restrict__ cnt, const int* __restrict__ partial,
                       int* __restrict__ offs, int n) {
    __shared__ int s[BLK];
    int base = blockIdx.x * 1024;
    int t = threadIdx.x;
    int i0 = base + t * 4;
    int c[4]; int sum = 0;
#pragma unroll
    for (int k = 0; k < 4; ++k) {
        int i = i0 + k;
        c[k] = (i < n) ? cnt[i] : 0;
        sum += c[k];
    }
    s[t] = sum; __syncthreads();
    for (int st = 1; st < BLK; st <<= 1) {
        int v = (t >= st) ? s[t - st] : 0;
        __syncthreads();
        s[t] += v;
        __syncthreads();
    }
    int ex = (t == 0) ? 0 : s[t - 1];
    ex += partial[blockIdx.x];
#pragma unroll
    for (int k = 0; k < 4; ++k) {
        int i = i0 + k;
        if (i < n) { offs[i] = ex; ex += c[k]; }
    }
}

// K3: fold emb through gcn: Wfull[0,j]=gcn_W[0,j]; Wfull[1+m,j]=emb_W[m,:]@gcn_W[1:,j]
__global__ void k3_weights(const float* __restrict__ emb_W, const float* __restrict__ emb_b,
                           const float* __restrict__ gcn_W,
                           float* __restrict__ Wfull, float* __restrict__ hWbias) {
    int t = threadIdx.x;
    for (int idx = t; idx < 64 * 32; idx += blockDim.x) {
        int k = idx >> 5, j = idx & 31;
        float acc;
        if (k == 0) {
            acc = gcn_W[j];
        } else {
            int m = k - 1;
            acc = 0.0f;
            for (int tt = 0; tt < 63; ++tt)
                acc += emb_W[m * 63 + tt] * gcn_W[(1 + tt) * 32 + j];
        }
        Wfull[idx] = acc;
    }
    if (t < 32) {
        float acc = 0.0f;
        for (int tt = 0; tt < 63; ++tt)
            acc += emb_b[tt] * gcn_W[(1 + tt) * 32 + t];
        hWbias[t] = acc;
    }
}

// K4: hWs[n,:] = dinv[n] * (x[n,:] @ Wfull + hWbias)   -- dinv[row] folded in
__global__ void k4_gemm(const float* __restrict__ x, const float* __restrict__ Wfull,
                        const float* __restrict__ hWbias, const float* __restrict__ dinv,
                        float* __restrict__ hWs, int n_nodes) {
    __shared__ float Wl[64 * 32];
    __shared__ float xs[8 * 64];
    int tid = threadIdx.x;
    for (int idx = tid; idx < 2048; idx += BLK) Wl[idx] = Wfull[idx];
    int rowBase = blockIdx.x * 8;
    for (int idx = tid; idx < 512; idx += BLK) {
        int r = rowBase + (idx >> 6);
        xs[idx] = (r < n_nodes) ? x[(size_t)r * 64 + (idx & 63)] : 0.0f;
    }
    __syncthreads();
    int j = tid & 31, lr = tid >> 5;
    int n = rowBase + lr;
    if (n < n_nodes) {
        float acc = hWbias[j];
#pragma unroll
        for (int k = 0; k < 64; ++k)
            acc += xs[lr * 64 + k] * Wl[k * 32 + j];
        hWs[(size_t)n * 32 + j] = dinv[n] * acc;
    }
}

// K5a: XCD-partitioned CSR scatter. slice = blockIdx&7 handles cols in
// partition slice; sibling blocks (same chunk, different slice) share the
// edge-chunk reads via L2/L3. Each XCD's csr slice (~1.5MB) stays L2-resident.
__global__ void k5a_scatter(const int* __restrict__ row, const int* __restrict__ col,
                            const uint8_t* __restrict__ ewc, int* __restrict__ offs,
                            int* __restrict__ csr, int n_edges, float part_scale) {
    int slice = blockIdx.x & 7;
    int g = blockIdx.x >> 3;
    int nchunks = gridDim.x >> 3;
    int chunk = (n_edges + nchunks - 1) / nchunks;
    int e0 = g * chunk;
    int e1 = min(e0 + chunk, n_edges);
    for (int e = e0 + threadIdx.x; e < e1; e += BLK) {
        int c = col[e];
        int part = (int)((float)c * part_scale);   // consistent everywhere
        part = min(part, 7);
        if (part == slice) {
            int r = row[e];
            int cls = ewc[e] & 3;
            int pos = atomicAdd(&offs[c], 1);
            csr[pos] = (r << 2) | cls;
        }
    }
}

// K5b: gather-aggregate + self-loop + bias + relu + pool. 32 lanes per node.
// Software-pipelined: csr entry 2-deep, hWs vector 1-deep.
__global__ void k5b_gather(const int* __restrict__ offs, const int* __restrict__ cnt,
                           const int* __restrict__ csr, const float* __restrict__ hWs,
                           const float* __restrict__ dinv, const float* __restrict__ mw,
                           const float* __restrict__ gcn_b, const int* __restrict__ batch,
                           float* __restrict__ pooled, int n_nodes) {
    int n = blockIdx.x * 8 + (threadIdx.x >> 5);
    int j = threadIdx.x & 31;
    if (n >= n_nodes) return;
    float a = mw[0], b = mw[1], c3 = mw[2];
    float m = fmaxf(a, fmaxf(b, c3));
    float ea = __expf(a - m), eb = __expf(b - m), ec = __expf(c3 - m);
    float inv = 1.0f / (ea + eb + ec);
    float s0 = ea * inv, s1 = eb * inv, s2 = ec * inv;

    int end = offs[n];            // mutated by k5a: now the end pointer
    int start = end - cnt[n];
    float acc = 0.0f;
    int p = start;
    int pk0 = (p < end) ? csr[p] : 0;
    float v0 = (p < end) ? hWs[(size_t)(pk0 >> 2) * 32 + j] : 0.0f;
    int pk1 = (p + 1 < end) ? csr[p + 1] : 0;
    for (; p < end; ++p) {
        int pk = pk0;
        float v = v0;
        pk0 = pk1;
        if (p + 1 < end) v0 = hWs[(size_t)(pk0 >> 2) * 32 + j];
        if (p + 2 < end) pk1 = csr[p + 2];
        int cls = pk & 3;
        float w = (cls & 2) ? ((cls & 1) ? 1.0f : s2) : ((cls & 1) ? s1 : s0);
        acc += w * v;
    }
    float di = dinv[n];
    float aa = di * (acc + hWs[(size_t)n * 32 + j]) + gcn_b[j];
    float hg = fmaxf(aa, 0.0f);
    atomicAdd(&pooled[batch[n] * 32 + j], hg);
}

// K7: head: z = relu(pooled @ fc1_W + fc1_b); out = z @ out_W + out_b
__global__ void k7_head(const float* __restrict__ pooled, const float* __restrict__ fc1_W,
                        const float* __restrict__ fc1_b, const float* __restrict__ out_W,
                        const float* __restrict__ out_b, float* __restrict__ out,
                        int n_graphs) {
    __shared__ float Wl[32 * 32];
    __shared__ float bl[32];
    __shared__ float owl[32];
    int t = threadIdx.x;
    for (int idx = t; idx < 1024; idx += BLK) Wl[idx] = fc1_W[idx];
    if (t < 32) { bl[t] = fc1_b[t]; owl[t] = out_W[t]; }
    __syncthreads();
    if (t < n_graphs) {
        float p[32];
#pragma unroll
        for (int k = 0; k < 32; ++k) p[k] = pooled[t * 32 + k];
        float acc = 0.0f;
        for (int j = 0; j < 32; ++j) {
            float z = bl[j];
#pragma unroll
            for (int k = 0; k < 32; ++k) z += p[k] * Wl[k * 32 + j];
            z = fmaxf(z, 0.0f);
            acc += z * owl[j];
        }
        out[t] = acc + out_b[0];
    }
}

extern "C" void kernel_launch(void* const* d_in, const int* in_sizes, int n_in,
                              void* d_out, int out_size, void* d_ws, size_t ws_size,
                              hipStream_t stream) {
    const float* x     = (const float*)d_in[0];
    const int*   ei    = (const int*)d_in[1];
    const int*   batch = (const int*)d_in[2];
    const int*   km    = (const int*)d_in[3];
    const int*   um    = (const int*)d_in[4];
    const int*   om    = (const int*)d_in[5];
    const float* mw    = (const float*)d_in[6];
    const float* emb_W = (const float*)d_in[7];
    const float* emb_b = (const float*)d_in[8];
    const float* gcn_W = (const float*)d_in[9];
    const float* gcn_b = (const float*)d_in[10];
    const float* fc1_W = (const float*)d_in[11];
    const float* fc1_b = (const float*)d_in[12];
    const float* out_W = (const float*)d_in[13];
    const float* out_b = (const float*)d_in[14];

    const int n_nodes  = in_sizes[0] / 64;
    const int n_edges  = in_sizes[1] / 2;
    const int s0 = in_sizes[3], s1 = in_sizes[4], s2 = in_sizes[5];
    const int n_graphs = out_size;  // 256

    const int* row = ei;
    const int* col = ei + n_edges;

    // ---- workspace layout (~29 MB) ----
    char* base = (char*)d_ws;
    int*     cnt     = (int*)base;     base += (size_t)n_nodes * 4;       // } zeroed
    float*   degf    = (float*)base;   base += (size_t)n_nodes * 4;       // } together
    float*   pooled  = (float*)base;   base += (size_t)n_graphs * 32 * 4; // }
    int*     offs    = (int*)base;     base += (size_t)n_nodes * 4;
    int*     partial = (int*)base;     base += 256 * 4;
    float*   Wfull   = (float*)base;   base += 2048 * 4;
    float*   hWbias  = (float*)base;   base += 32 * 4;
    uint8_t* ewc     = (uint8_t*)base; base += ((size_t)n_edges + 15) & ~15ull;
    int*     csr     = (int*)base;     base += (size_t)n_edges * 4;
    float*   hWs     = (float*)base;   base += (size_t)n_nodes * 32 * 4;

    hipMemsetAsync(cnt, 0, ((size_t)2 * n_nodes + (size_t)n_graphs * 32) * sizeof(float), stream);

    k0_hist<<<(n_edges + BLK - 1) / BLK, BLK, 0, stream>>>(col, cnt, ewc, n_edges);
    k1_class_deg<<<(s0 + s1 + s2 + BLK - 1) / BLK, BLK, 0, stream>>>(
        km, um, om, s0, s1, s2, col, mw, ewc, degf);
    k2_dinv<<<(n_nodes + BLK - 1) / BLK, BLK, 0, stream>>>(degf, n_nodes);

    int nb = (n_nodes + 1023) / 1024;   // 98 for N=100000; kscanB handles nb<=256
    kscanA<<<nb, BLK, 0, stream>>>(cnt, partial, n_nodes);
    kscanB<<<1, BLK, 0, stream>>>(partial, nb);
    kscanC<<<nb, BLK, 0, stream>>>(cnt, partial, offs, n_nodes);

    k3_weights<<<1, BLK, 0, stream>>>(emb_W, emb_b, gcn_W, Wfull, hWbias);
    k4_gemm<<<(n_nodes + 7) / 8, BLK, 0, stream>>>(x, Wfull, hWbias, degf, hWs, n_nodes);

    float part_scale = 8.0f / (float)n_nodes;
    k5a_scatter<<<2048, BLK, 0, stream>>>(row, col, ewc, offs, csr, n_edges, part_scale);
    k5b_gather<<<(n_nodes + 7) / 8, BLK, 0, stream>>>(
        offs, cnt, csr, hWs, degf, mw, gcn_b, batch, pooled, n_nodes);

    k7_head<<<1, BLK, 0, stream>>>(pooled, fc1_W, fc1_b, out_W, out_b, (float*)d_out, n_graphs);
}

// Round 4
// 651.528 us; speedup vs baseline: 1.3780x; 1.1805x over previous
//
#include <hip/hip_runtime.h>
#include <hip/hip_fp16.h>
#include <stdint.h>

// GCN forward. N=100000, E=3000000, G=256, F_IN=64, NHID=32.
// R1: 96M scatter-atomics = L2 atomic ceiling (312us). -> CSR gather.
// R2: naive CSR build = 16x write amplification across 8 incoherent L2s.
// R3: XCD-sliced build OK; gather = 3M random 128B lines @1.5TB/s (195us);
//     hidden cost: every random col[e] 4B gather touches a 64B line.
// R4: fp16 hWs (64B lines, deeper pipeline); degrees derived from the
//     sorted CSR (no col gathers anywhere); 4-slice CSR build.

#define BLK 256

// K0: in-degree histogram (sequential col read, atomics on 400KB cnt)
__global__ void k0_hist(const int* __restrict__ col, int* __restrict__ cnt, int n_edges) {
    int i = blockIdx.x * blockDim.x + threadIdx.x;
    if (i < n_edges) atomicAdd(&cnt[col[i]], 1);
}

// K1: edge class from masks. Masks cover all E exactly (E%3==0).
// Random 1B writes into 3MB ewc: fits each XCD L2 -> no thrash.
__global__ void k1_cls(const int* __restrict__ km, const int* __restrict__ um,
                       const int* __restrict__ om, int s0, int s1, int s2,
                       uint8_t* __restrict__ ewc) {
    int i = blockIdx.x * blockDim.x + threadIdx.x;
    int total = s0 + s1 + s2;
    if (i >= total) return;
    int e, cls;
    if (i < s0)           { e = km[i];           cls = 0; }
    else if (i < s0 + s1) { e = um[i - s0];      cls = 1; }
    else                  { e = om[i - s0 - s1]; cls = 2; }
    ewc[e] = (uint8_t)cls;
}

// ---- exclusive scan of cnt[N] -> offs[N] ----
__global__ void kscanA(const int* __restrict__ cnt, int* __restrict__ partial, int n) {
    __shared__ int s[BLK];
    int base = blockIdx.x * 1024;
    int t = threadIdx.x;
    int sum = 0;
#pragma unroll
    for (int k = 0; k < 4; ++k) {
        int i = base + t * 4 + k;
        if (i < n) sum += cnt[i];
    }
    s[t] = sum; __syncthreads();
    for (int st = BLK / 2; st > 0; st >>= 1) {
        if (t < st) s[t] += s[t + st];
        __syncthreads();
    }
    if (t == 0) partial[blockIdx.x] = s[0];
}

__global__ void kscanB(int* __restrict__ partial, int nb) {
    __shared__ int s[BLK];
    int t = threadIdx.x;
    s[t] = (t < nb) ? partial[t] : 0; __syncthreads();
    for (int st = 1; st < BLK; st <<= 1) {
        int v = (t >= st) ? s[t - st] : 0;
        __syncthreads();
        s[t] += v;
        __syncthreads();
    }
    if (t < nb) partial[t] = (t == 0) ? 0 : s[t - 1];  // exclusive
}

__global__ void kscanC(const int* __restrict__ cnt, const int* __restrict__ partial,
                       int* __restrict__ offs, int n) {
    __shared__ int s[BLK];
    int base = blockIdx.x * 1024;
    int t = threadIdx.x;
    int i0 = base + t * 4;
    int c[4]; int sum = 0;
#pragma unroll
    for (int k = 0; k < 4; ++k) {
        int i = i0 + k;
        c[k] = (i < n) ? cnt[i] : 0;
        sum += c[k];
    }
    s[t] = sum; __syncthreads();
    for (int st = 1; st < BLK; st <<= 1) {
        int v = (t >= st) ? s[t - st] : 0;
        __syncthreads();
        s[t] += v;
        __syncthreads();
    }
    int ex = (t == 0) ? 0 : s[t - 1];
    ex += partial[blockIdx.x];
#pragma unroll
    for (int k = 0; k < 4; ++k) {
        int i = i0 + k;
        if (i < n) { offs[i] = ex; ex += c[k]; }
    }
}

// K5a: 4-slice XCD-partitioned CSR scatter; csr[pos] = (row<<2)|cls.
// Sequential col/row/ewc reads per chunk; each ~3MB csr slice stays
// L2-resident (two XCDs share a slice; byte-granular writeback merges).
__global__ void k5a_scatter(const int* __restrict__ row, const int* __restrict__ col,
                            const uint8_t* __restrict__ ewc, int* __restrict__ offs,
                            int* __restrict__ csr, int n_edges, float part_scale) {
    int slice = blockIdx.x & 3;
    int g = blockIdx.x >> 2;
    int nchunks = gridDim.x >> 2;
    int chunk = (n_edges + nchunks - 1) / nchunks;
    int e0 = g * chunk;
    int e1 = min(e0 + chunk, n_edges);
    for (int e = e0 + threadIdx.x; e < e1; e += BLK) {
        int c = col[e];
        int part = min((int)((float)c * part_scale), 3);
        if (part == slice) {
            int pos = atomicAdd(&offs[c], 1);
            csr[pos] = (row[e] << 2) | (ewc[e] & 3);
        }
    }
}

// K2: per-node degree from CSR class counts -> dinv = rsqrt(deg+1).
// offs has been mutated by k5a to END offsets; start = end - cnt.
__global__ void k2_deg(const int* __restrict__ offs, const int* __restrict__ cnt,
                       const int* __restrict__ csr, const float* __restrict__ mw,
                       float* __restrict__ dinv, int n_nodes) {
    int n = blockIdx.x * blockDim.x + threadIdx.x;
    if (n >= n_nodes) return;
    float a = mw[0], b = mw[1], c3 = mw[2];
    float m = fmaxf(a, fmaxf(b, c3));
    float ea = __expf(a - m), eb = __expf(b - m), ec = __expf(c3 - m);
    float inv = 1.0f / (ea + eb + ec);
    float s0 = ea * inv, s1 = eb * inv, s2 = ec * inv;
    int end = offs[n];
    int p = end - cnt[n];
    int c0 = 0, c1 = 0, c2 = 0;
    for (; p < end; ++p) {
        int cls = csr[p] & 3;
        c0 += (cls == 0); c1 += (cls == 1); c2 += (cls == 2);
    }
    float deg = s0 * (float)c0 + s1 * (float)c1 + s2 * (float)c2 + 1.0f;
    dinv[n] = rsqrtf(deg);
}

// K3: fold emb through gcn: Wfull[0,j]=gcn_W[0,j]; Wfull[1+m,j]=emb_W[m,:]@gcn_W[1:,j]
__global__ void k3_weights(const float* __restrict__ emb_W, const float* __restrict__ emb_b,
                           const float* __restrict__ gcn_W,
                           float* __restrict__ Wfull, float* __restrict__ hWbias) {
    int t = threadIdx.x;
    for (int idx = t; idx < 64 * 32; idx += blockDim.x) {
        int k = idx >> 5, j = idx & 31;
        float acc;
        if (k == 0) {
            acc = gcn_W[j];
        } else {
            int m = k - 1;
            acc = 0.0f;
            for (int tt = 0; tt < 63; ++tt)
                acc += emb_W[m * 63 + tt] * gcn_W[(1 + tt) * 32 + j];
        }
        Wfull[idx] = acc;
    }
    if (t < 32) {
        float acc = 0.0f;
        for (int tt = 0; tt < 63; ++tt)
            acc += emb_b[tt] * gcn_W[(1 + tt) * 32 + t];
        hWbias[t] = acc;
    }
}

// K4: hWs[n,:] = fp16( dinv[n] * (x[n,:] @ Wfull + hWbias) )
__global__ void k4_gemm(const float* __restrict__ x, const float* __restrict__ Wfull,
                        const float* __restrict__ hWbias, const float* __restrict__ dinv,
                        __half* __restrict__ hWs, int n_nodes) {
    __shared__ float Wl[64 * 32];
    __shared__ float xs[8 * 64];
    int tid = threadIdx.x;
    for (int idx = tid; idx < 2048; idx += BLK) Wl[idx] = Wfull[idx];
    int rowBase = blockIdx.x * 8;
    for (int idx = tid; idx < 512; idx += BLK) {
        int r = rowBase + (idx >> 6);
        xs[idx] = (r < n_nodes) ? x[(size_t)r * 64 + (idx & 63)] : 0.0f;
    }
    __syncthreads();
    int j = tid & 31, lr = tid >> 5;
    int n = rowBase + lr;
    if (n < n_nodes) {
        float acc = hWbias[j];
#pragma unroll
        for (int k = 0; k < 64; ++k)
            acc += xs[lr * 64 + k] * Wl[k * 32 + j];
        hWs[(size_t)n * 32 + j] = __float2half(dinv[n] * acc);
    }
}

// K5b: gather-aggregate + self-loop + bias + relu + pool.
// 16 lanes per node, half2 per lane; 2-edge unrolled pipeline
// (2 value + 2 csr loads in flight).
__global__ void k5b_gather(const int* __restrict__ offs, const int* __restrict__ cnt,
                           const int* __restrict__ csr, const __half2* __restrict__ hws2,
                           const float* __restrict__ dinv, const float* __restrict__ mw,
                           const float* __restrict__ gcn_b, const int* __restrict__ batch,
                           float* __restrict__ pooled, int n_nodes) {
    int n = blockIdx.x * 16 + (threadIdx.x >> 4);
    int j2 = threadIdx.x & 15;
    if (n >= n_nodes) return;
    float a = mw[0], b = mw[1], c3 = mw[2];
    float m = fmaxf(a, fmaxf(b, c3));
    float ea = __expf(a - m), eb = __expf(b - m), ec = __expf(c3 - m);
    float inv = 1.0f / (ea + eb + ec);
    float s0 = ea * inv, s1 = eb * inv, s2 = ec * inv;

    int end = offs[n];
    int p = end - cnt[n];
    int rem = end - p;
    float accx = 0.0f, accy = 0.0f;
    int pk0 = 0, pk1 = 0, pk2 = 0, pk3 = 0;
    __half2 v0 = __float2half2_rn(0.0f), v1 = __float2half2_rn(0.0f);
    if (rem > 0) pk0 = csr[p];
    if (rem > 1) pk1 = csr[p + 1];
    if (rem > 2) pk2 = csr[p + 2];
    if (rem > 3) pk3 = csr[p + 3];
    if (rem > 0) v0 = hws2[(size_t)(pk0 >> 2) * 16 + j2];
    if (rem > 1) v1 = hws2[(size_t)(pk1 >> 2) * 16 + j2];
    while (rem >= 2) {
        int cA = pk0 & 3, cB = pk1 & 3;
        float2 fA = __half22float2(v0), fB = __half22float2(v1);
        pk0 = pk2; pk1 = pk3;
        if (rem > 4) pk2 = csr[p + 4];
        if (rem > 5) pk3 = csr[p + 5];
        if (rem > 2) v0 = hws2[(size_t)(pk0 >> 2) * 16 + j2];
        if (rem > 3) v1 = hws2[(size_t)(pk1 >> 2) * 16 + j2];
        float wA = (cA == 0) ? s0 : ((cA == 1) ? s1 : s2);
        float wB = (cB == 0) ? s0 : ((cB == 1) ? s1 : s2);
        accx += wA * fA.x + wB * fB.x;
        accy += wA * fA.y + wB * fB.y;
        p += 2; rem -= 2;
    }
    if (rem == 1) {
        int cA = pk0 & 3;
        float wA = (cA == 0) ? s0 : ((cA == 1) ? s1 : s2);
        float2 fA = __half22float2(v0);
        accx += wA * fA.x;
        accy += wA * fA.y;
    }
    float2 self = __half22float2(hws2[(size_t)n * 16 + j2]);
    float di = dinv[n];
    float rx = fmaxf(di * (accx + self.x) + gcn_b[2 * j2], 0.0f);
    float ry = fmaxf(di * (accy + self.y) + gcn_b[2 * j2 + 1], 0.0f);
    int g = batch[n];
    atomicAdd(&pooled[g * 32 + 2 * j2], rx);
    atomicAdd(&pooled[g * 32 + 2 * j2 + 1], ry);
}

// K7: head: z = relu(pooled @ fc1_W + fc1_b); out = z @ out_W + out_b
__global__ void k7_head(const float* __restrict__ pooled, const float* __restrict__ fc1_W,
                        const float* __restrict__ fc1_b, const float* __restrict__ out_W,
                        const float* __restrict__ out_b, float* __restrict__ out,
                        int n_graphs) {
    __shared__ float Wl[32 * 32];
    __shared__ float bl[32];
    __shared__ float owl[32];
    int t = threadIdx.x;
    for (int idx = t; idx < 1024; idx += BLK) Wl[idx] = fc1_W[idx];
    if (t < 32) { bl[t] = fc1_b[t]; owl[t] = out_W[t]; }
    __syncthreads();
    if (t < n_graphs) {
        float p[32];
#pragma unroll
        for (int k = 0; k < 32; ++k) p[k] = pooled[t * 32 + k];
        float acc = 0.0f;
        for (int j = 0; j < 32; ++j) {
            float z = bl[j];
#pragma unroll
            for (int k = 0; k < 32; ++k) z += p[k] * Wl[k * 32 + j];
            z = fmaxf(z, 0.0f);
            acc += z * owl[j];
        }
        out[t] = acc + out_b[0];
    }
}

static inline size_t align_up(size_t v, size_t a) { return (v + a - 1) & ~(a - 1); }

extern "C" void kernel_launch(void* const* d_in, const int* in_sizes, int n_in,
                              void* d_out, int out_size, void* d_ws, size_t ws_size,
                              hipStream_t stream) {
    const float* x     = (const float*)d_in[0];
    const int*   ei    = (const int*)d_in[1];
    const int*   batch = (const int*)d_in[2];
    const int*   km    = (const int*)d_in[3];
    const int*   um    = (const int*)d_in[4];
    const int*   om    = (const int*)d_in[5];
    const float* mw    = (const float*)d_in[6];
    const float* emb_W = (const float*)d_in[7];
    const float* emb_b = (const float*)d_in[8];
    const float* gcn_W = (const float*)d_in[9];
    const float* gcn_b = (const float*)d_in[10];
    const float* fc1_W = (const float*)d_in[11];
    const float* fc1_b = (const float*)d_in[12];
    const float* out_W = (const float*)d_in[13];
    const float* out_b = (const float*)d_in[14];

    const int n_nodes  = in_sizes[0] / 64;
    const int n_edges  = in_sizes[1] / 2;
    const int s0 = in_sizes[3], s1 = in_sizes[4], s2 = in_sizes[5];
    const int n_graphs = out_size;  // 256

    const int* row = ei;
    const int* col = ei + n_edges;

    // ---- workspace layout (~23 MB) ----
    char* base = (char*)d_ws;
    int*     cnt     = (int*)base;     base += (size_t)n_nodes * 4;       // } zeroed
    float*   pooled  = (float*)base;   base += (size_t)n_graphs * 32 * 4; // } together
    int*     offs    = (int*)base;     base += (size_t)n_nodes * 4;
    int*     partial = (int*)base;     base += 256 * 4;
    float*   dinv    = (float*)base;   base += (size_t)n_nodes * 4;
    float*   Wfull   = (float*)base;   base += 2048 * 4;
    float*   hWbias  = (float*)base;   base += 32 * 4;
    uint8_t* ewc     = (uint8_t*)base; base += align_up((size_t)n_edges, 64);
    int*     csr     = (int*)base;     base += (size_t)n_edges * 4;
    base = (char*)align_up((size_t)base, 64);
    __half*  hWs     = (__half*)base;  base += (size_t)n_nodes * 32 * 2;

    hipMemsetAsync(cnt, 0, ((size_t)n_nodes + (size_t)n_graphs * 32) * 4, stream);

    k0_hist<<<(n_edges + BLK - 1) / BLK, BLK, 0, stream>>>(col, cnt, n_edges);
    k1_cls<<<(s0 + s1 + s2 + BLK - 1) / BLK, BLK, 0, stream>>>(km, um, om, s0, s1, s2, ewc);

    int nb = (n_nodes + 1023) / 1024;   // 98 for N=100000
    kscanA<<<nb, BLK, 0, stream>>>(cnt, partial, n_nodes);
    kscanB<<<1, BLK, 0, stream>>>(partial, nb);
    kscanC<<<nb, BLK, 0, stream>>>(cnt, partial, offs, n_nodes);

    float part_scale = 4.0f / (float)n_nodes;
    k5a_scatter<<<2048, BLK, 0, stream>>>(row, col, ewc, offs, csr, n_edges, part_scale);

    k2_deg<<<(n_nodes + BLK - 1) / BLK, BLK, 0, stream>>>(offs, cnt, csr, mw, dinv, n_nodes);

    k3_weights<<<1, BLK, 0, stream>>>(emb_W, emb_b, gcn_W, Wfull, hWbias);
    k4_gemm<<<(n_nodes + 7) / 8, BLK, 0, stream>>>(x, Wfull, hWbias, dinv, hWs, n_nodes);

    k5b_gather<<<(n_nodes + 15) / 16, BLK, 0, stream>>>(
        offs, cnt, csr, (const __half2*)hWs, dinv, mw, gcn_b, batch, pooled, n_nodes);

    k7_head<<<1, BLK, 0, stream>>>(pooled, fc1_W, fc1_b, out_W, out_b, (float*)d_out, n_graphs);
}